// Round 2
// baseline (188.419 us; speedup 1.0000x reference)
//
#include <hip/hip_runtime.h>

// CausalSelfAttention on MI355X (gfx950), bf16 MFMA pipeline.
// B=2 T=2048 C=1024 NH=16 HD=64.  M=B*T=4096.

typedef __attribute__((ext_vector_type(8))) short short8;   // 8 x bf16 (4 VGPR)
typedef __attribute__((ext_vector_type(4))) short short4v;  // 4 x bf16 (2 VGPR)
typedef __attribute__((ext_vector_type(4))) float f32x4;    // MFMA 16x16 acc
typedef __attribute__((ext_vector_type(2))) unsigned int u32x2;
struct ushort4_t { unsigned short x, y, z, w; };

#define MFMA16(a, b, c) __builtin_amdgcn_mfma_f32_16x16x32_bf16((a), (b), (c), 0, 0, 0)
#define MFMA16K16(a, b, c) __builtin_amdgcn_mfma_f32_16x16x16bf16_1k((a), (b), (c), 0, 0, 0)

__device__ __forceinline__ unsigned short f2bf(float f) {
  unsigned u = __builtin_bit_cast(unsigned, f);
  u += 0x7fffu + ((u >> 16) & 1u);   // RNE
  return (unsigned short)(u >> 16);
}

__device__ __forceinline__ unsigned short f2bf_fast(float f) {
  // round-half-up: cheaper (2 VALU); |err| <= 2^-9 rel, fine for P/y
  return (unsigned short)((__builtin_bit_cast(unsigned, f) + 0x8000u) >> 16);
}

#if __has_builtin(__builtin_amdgcn_cvt_pk_bf16_f32)
typedef __attribute__((ext_vector_type(2))) __bf16 bf16x2;
__device__ __forceinline__ short4v pack_bf16x4(float a, float b, float c, float d) {
  bf16x2 lo = __builtin_amdgcn_cvt_pk_bf16_f32(a, b);
  bf16x2 hi = __builtin_amdgcn_cvt_pk_bf16_f32(c, d);
  u32x2 t;
  t[0] = __builtin_bit_cast(unsigned, lo);
  t[1] = __builtin_bit_cast(unsigned, hi);
  return __builtin_bit_cast(short4v, t);
}
#else
__device__ __forceinline__ short4v pack_bf16x4(float a, float b, float c, float d) {
  short4v r;
  r[0] = (short)f2bf_fast(a); r[1] = (short)f2bf_fast(b);
  r[2] = (short)f2bf_fast(c); r[3] = (short)f2bf_fast(d);
  return r;
}
#endif

__device__ __forceinline__ void gl2lds16(const void* g, void* l) {
  // async global->LDS, 16B/lane; LDS dest = wave-uniform base + lane*16
  __builtin_amdgcn_global_load_lds(
      (__attribute__((address_space(1))) void*)g,
      (__attribute__((address_space(3))) void*)l,
      16, 0, 0);
}

// ---------------- fp32 -> bf16 flat convert ----------------
__global__ __launch_bounds__(256) void conv_bf16(const float* __restrict__ src,
                                                 unsigned short* __restrict__ dst,
                                                 int n) {
  int i = (blockIdx.x * 256 + threadIdx.x) * 4;
  if (i >= n) return;
  float4 f = *(const float4*)(src + i);
  unsigned long long r = (unsigned long long)f2bf(f.x)
      | ((unsigned long long)f2bf(f.y) << 16)
      | ((unsigned long long)f2bf(f.z) << 32)
      | ((unsigned long long)f2bf(f.w) << 48);
  *(unsigned long long*)(dst + i) = r;
}

// ---------------- fp32 (K x N) -> bf16 transposed (N x K) ----------------
__global__ __launch_bounds__(256) void transpose_conv(const float* __restrict__ W,
                                                      unsigned short* __restrict__ WT,
                                                      int K, int N) {
  __shared__ float tile[64][65];
  const int n0 = blockIdx.x * 64, k0 = blockIdx.y * 64;
  const int tid = threadIdx.x;
  const int c = tid & 63, rbase = tid >> 6;  // 4 rows per pass, 16 passes
#pragma unroll
  for (int i = 0; i < 16; ++i) {
    int r = i * 4 + rbase;
    tile[r][c] = W[(size_t)(k0 + r) * N + n0 + c];
  }
  __syncthreads();
#pragma unroll
  for (int i = 0; i < 16; ++i) {
    int r = i * 4 + rbase;
    WT[(size_t)(n0 + r) * K + k0 + c] = f2bf(tile[c][r]);
  }
}

// ---------------- GEMM: C = A(MxK) * BT(NxK)^T ----------------
// BK=64, XOR-swizzled LDS staging (conflict-free ds_read_b128 fragments).
// MT = M-tile (64); N-tile fixed 128.
// R13 (this round): triple-buffered K-tile pipeline, staged TWO tiles ahead,
// raw s_barrier + counted s_waitcnt vmcnt(NSTG) — ports the attn kernel's
// proven DMA pipeline.  Old structure had TWO __syncthreads per K-step, each
// draining vmcnt(0): ~16 full L2-latency bubbles per block (K=1024), which is
// why QKV gemm sat at 537 TF / MfmaUtil 20%.  Now the newest stage (NSTG DMA
// instrs) stays in flight across the single per-tile barrier; stage(kt+2)
// overwrites the buffer of tile kt-1, which the barrier for tile kt proves
// consumed (same argument as attn).  MT=64 keeps LDS at 72 KB -> 2 blocks/CU
// resident so cross-block TLP covers residual stalls (m232 lesson: 4-wave
// deep pipelines at 1 block/CU don't self-overlap).
// EPI==0: QKV epilogue -> q (B,H,T,D) PRE-SCALED by 0.125*log2(e),
//         k (B,H,T,D), v (B,H,D,T) bf16 (v packed as ushort4)
// EPI==1: proj epilogue -> fp32 out + bias
template <int EPI, int MT>
__global__ __launch_bounds__(256)
void gemm_bt(const unsigned short* __restrict__ A,
             const unsigned short* __restrict__ BT,
             const float* __restrict__ bias,
             float* __restrict__ outF,
             unsigned short* __restrict__ q_out,
             unsigned short* __restrict__ k_out,
             unsigned short* __restrict__ vT_out,
             int Ndim, int Kdim) {
  constexpr int IF = MT / 32;                 // A-frags per wave per ksub
  constexpr int RA = MT / 32;                 // A staging rounds (32 rows each)
  constexpr int NSTG = RA + 4;                // DMA instrs per stage per thread
  constexpr int WAIT_KEEP1 = 0x0F70 + NSTG;   // vmcnt(NSTG): all but newest stage
  __shared__ __align__(16) unsigned short As[3][MT * 64];
  __shared__ __align__(16) unsigned short Bs[3][128 * 64];
  const int tid = threadIdx.x;
  const int wave = tid >> 6, lane = tid & 63;
  const int quad = lane >> 4, lr = lane & 15;
  const int wm = wave >> 1, wn = wave & 1;
  const int m0 = blockIdx.y * MT, n0 = blockIdx.x * 128;

  const int r_l = tid >> 3;
  const int cg = (tid & 7) ^ (r_l & 7);
  const unsigned short* gA = A + (size_t)(m0 + r_l) * Kdim + cg * 8;
  const unsigned short* gB = BT + (size_t)(n0 + r_l) * Kdim + cg * 8;
  const size_t rstep = (size_t)32 * Kdim;
  const int NT = Kdim >> 6;                   // K-tiles of 64

  auto stageT = [&](int bufi, int kt) {
#pragma unroll
    for (int rd = 0; rd < RA; ++rd)
      gl2lds16(gA + kt * 64 + rd * rstep, &As[bufi][rd * 2048 + wave * 512]);
#pragma unroll
    for (int rd = 0; rd < 4; ++rd)
      gl2lds16(gB + kt * 64 + rd * rstep, &Bs[bufi][rd * 2048 + wave * 512]);
  };

  f32x4 acc[IF][4] = {};
  stageT(0, 0);
  if (NT > 1) stageT(1, 1);
  int bufc = 0;
  for (int kt = 0; kt < NT; ++kt) {
    // Drain own DMAs for tile kt (issued 2 iters ago) but keep the newest
    // stage (NSTG instrs, tile kt+1) in flight.  The barrier then guarantees
    // all waves' contributions to tile kt are in LDS.
    if (kt < NT - 1) __builtin_amdgcn_s_waitcnt(WAIT_KEEP1);
    else             __builtin_amdgcn_s_waitcnt(0x0F70);   // vmcnt(0)
    __builtin_amdgcn_s_barrier();
    if (kt + 2 < NT) {
      int nb = bufc + 2; if (nb >= 3) nb -= 3;
      stageT(nb, kt + 2);         // overwrites buffer of tile kt-1 (consumed)
    }
    const unsigned short* Ab = As[bufc];
    const unsigned short* Bb = Bs[bufc];
#pragma unroll
    for (int s = 0; s < 2; ++s) {
      const int sw = ((s * 4 + quad) ^ (lr & 7)) * 8;
      short8 a[IF], b[4];
#pragma unroll
      for (int i = 0; i < IF; ++i)
        a[i] = *(const short8*)(Ab + (wm * (MT / 2) + i * 16 + lr) * 64 + sw);
#pragma unroll
      for (int j = 0; j < 4; ++j)
        b[j] = *(const short8*)(Bb + (wn * 64 + j * 16 + lr) * 64 + sw);
#pragma unroll
      for (int i = 0; i < IF; ++i)
#pragma unroll
        for (int j = 0; j < 4; ++j)
          acc[i][j] = MFMA16(a[i], b[j], acc[i][j]);
    }
    bufc += 1; if (bufc >= 3) bufc -= 3;
  }

  // C/D layout: col = lane&15, row = quad*4 + reg
  const int row_t = wm * (MT / 2) + quad * 4;
  const int col_t = wn * 64 + lr;
  if (EPI == 0) {
    const int sec = n0 >> 10;                 // block-uniform
    const float scl = (sec == 0) ? 0.18033688f : 1.0f;  // fold 0.125*log2(e) into Q
#pragma unroll
    for (int j = 0; j < 4; ++j) {
      const int n = n0 + col_t + j * 16;
      const float bi = bias[n];
      const int nn = n & 1023, h = nn >> 6, d = nn & 63;
#pragma unroll
      for (int i = 0; i < IF; ++i) {
        const int m_base = m0 + row_t + i * 16;   // 4 consecutive m for r=0..3
        const int bb = m_base >> 11, t0 = m_base & 2047;
        const int bh = bb * 16 + h;
        if (sec == 2) {
          ushort4_t pk;
          pk.x = f2bf(acc[i][j][0] + bi);
          pk.y = f2bf(acc[i][j][1] + bi);
          pk.z = f2bf(acc[i][j][2] + bi);
          pk.w = f2bf(acc[i][j][3] + bi);
          *(ushort4_t*)(vT_out + ((size_t)bh * 64 + d) * 2048 + t0) = pk;
        } else {
          unsigned short* dst = (sec == 0 ? q_out : k_out) + (size_t)bh * 131072 + t0 * 64 + d;
#pragma unroll
          for (int r = 0; r < 4; ++r)
            dst[r * 64] = f2bf((acc[i][j][r] + bi) * scl);
        }
      }
    }
  } else {
#pragma unroll
    for (int i = 0; i < IF; ++i)
#pragma unroll
      for (int r = 0; r < 4; ++r) {
        const int m = m0 + row_t + i * 16 + r;
#pragma unroll
        for (int j = 0; j < 4; ++j) {
          const int n = n0 + col_t + j * 16;
          outF[(size_t)m * Ndim + n] = acc[i][j][r] + bias[n];
        }
      }
  }
}

// ---------------- flash-style causal attention, 64-row q-tiles ----------------
// m=0 softmax; Q PRE-SCALED by 0.125*log2(e) so P = exp2(S).
// Transposed-S trick: S^T = K*Q^T; its C-layout IS the K=16 A-operand layout.
// Block = 4 waves x 16 q-rows = 64 q-rows; K/V fragment LDS reads shared.
// 1024 blocks, heavy-first (LPT) dispatch, bh%8 pins XCD for K/V L2 locality.
// Triple-buffered K/V staged TWO tiles ahead; raw s_barrier + manual
// s_waitcnt vmcnt(4) so the newest stage stays in flight across the barrier.
// q,k: (B,H,T,D); v: (B,H,D,T); y: (B,T,C).
__global__ __launch_bounds__(256, 3)
void attn(const unsigned short* __restrict__ qbuf,
          const unsigned short* __restrict__ kbuf,
          const unsigned short* __restrict__ vT,
          unsigned short* __restrict__ yb) {
  __shared__ __align__(16) unsigned short Ks[3][4096];
  __shared__ __align__(16) unsigned short Vs[3][4096];
  const int tid = threadIdx.x, wave = tid >> 6, lane = tid & 63;
  const int quad = lane >> 4, lr = lane & 15;
  const int bh = blockIdx.x;                  // heads fastest: bh%8 pins XCD
  const int qt = 31 - (int)blockIdx.y;        // heavy-first for refill (LPT)
  const int qrow0 = qt * 64;                  // tile base (head-local)

  const unsigned short* qp0 = qbuf + (size_t)bh * 131072;
  const unsigned short* kp0 = kbuf + (size_t)bh * 131072;
  const unsigned short* vp0 = vT   + (size_t)bh * 131072;

  // Q fragments (B-operand of S^T: n = q = lane&15, k = d = quad*8+j)
  short8 aq[2];
  {
    const unsigned short* qp =
        qp0 + (size_t)(qrow0 + wave * 16 + lr) * 64 + quad * 8;
    aq[0] = *(const short8*)qp;
    aq[1] = *(const short8*)(qp + 32);
  }

  short4v ones4;
#pragma unroll
  for (int i = 0; i < 4; ++i) ones4[i] = (short)0x3F80;  // bf16 1.0

  // DMA staging: thread t -> (row=t>>3 in 0..31 (+32), cg=(t&7)^(row&7))
  const int sr = tid >> 3;
  const int scg = (tid & 7) ^ (sr & 7);
  // K fragment bases (A-operand: m = key = lr (+jt*16), k = d = (quad+4h)*8), swizzled
  int kbase[2];
#pragma unroll
  for (int h = 0; h < 2; ++h)
    kbase[h] = lr * 64 + (((quad + 4 * h) ^ (lr & 7)) << 3);
  // V b64 bases per key-block kb: element (row = d = lr (+jd*16), col = kb*16+quad*4)
  int vbase[4];
#pragma unroll
  for (int kb = 0; kb < 4; ++kb)
    vbase[kb] = lr * 64 + (((2 * kb + (quad >> 1)) ^ (lr & 7)) << 3) + (quad & 1) * 4;

  f32x4 o[4] = {};
  f32x4 lacc = {};

  auto stage = [&](int buf, int kt) {
    const unsigned short* kg = kp0 + (size_t)(kt * 64 + sr) * 64 + scg * 8;
    const unsigned short* vg = vp0 + (size_t)sr * 2048 + kt * 64 + scg * 8;
    gl2lds16(kg,             &Ks[buf][wave * 512]);
    gl2lds16(kg + 32 * 64,   &Ks[buf][2048 + wave * 512]);
    gl2lds16(vg,             &Vs[buf][wave * 512]);
    gl2lds16(vg + 32 * 2048, &Vs[buf][2048 + wave * 512]);
  };

  const int dlast = qt;           // diagonal k-tile index == last tile
  stage(0, 0);
  if (dlast >= 1) stage(1, 1);
  int buf = 0;
  for (int kt = 0; kt <= dlast; ++kt) {
    // Drain own DMAs for tile kt (issued 2 iters ago) but keep the newest
    // stage (4 instrs, tile kt+1) in flight. Each wave drains its own; the
    // barrier then guarantees all waves' contributions to tile kt are in LDS.
    if (kt < dlast) __builtin_amdgcn_s_waitcnt(0x0F74);  // vmcnt(4)
    else            __builtin_amdgcn_s_waitcnt(0x0F70);  // vmcnt(0)
    __builtin_amdgcn_s_barrier();
    if (kt + 2 <= dlast) {
      int nb = buf + 2; if (nb >= 3) nb -= 3;
      stage(nb, kt + 2);          // overwrites buffer of tile kt-1 (consumed)
    }
    const unsigned short* Kb = Ks[buf];
    const unsigned short* Vb = Vs[buf];
    short8 bk[4][2];
#pragma unroll
    for (int jt = 0; jt < 4; ++jt) {
      bk[jt][0] = *(const short8*)(Kb + jt * 1024 + kbase[0]);
      bk[jt][1] = *(const short8*)(Kb + jt * 1024 + kbase[1]);
    }
    // S^T, exp2 (+causal mask on the diagonal tile), pack; lsum.
    f32x4 s[4] = {};
#pragma unroll
    for (int jt = 0; jt < 4; ++jt) {
      s[jt] = MFMA16(bk[jt][0], aq[0], s[jt]);
      s[jt] = MFMA16(bk[jt][1], aq[1], s[jt]);
    }
    short4v pa[4];
    if (kt == dlast) {            // diagonal: key-local > wave*16+lr masked
      const int qloc = wave * 16 + lr;
#pragma unroll
      for (int jt = 0; jt < 4; ++jt) {
        float p[4];
#pragma unroll
        for (int r = 0; r < 4; ++r) {
          p[r] = __builtin_amdgcn_exp2f(s[jt][r]);
          if (jt * 16 + quad * 4 + r > qloc) p[r] = 0.f;
        }
        pa[jt] = pack_bf16x4(p[0], p[1], p[2], p[3]);
      }
    } else {
#pragma unroll
      for (int jt = 0; jt < 4; ++jt) {
        float p[4];
#pragma unroll
        for (int r = 0; r < 4; ++r) p[r] = __builtin_amdgcn_exp2f(s[jt][r]);
        pa[jt] = pack_bf16x4(p[0], p[1], p[2], p[3]);
      }
    }
#pragma unroll
    for (int kb = 0; kb < 4; ++kb)
      lacc = MFMA16K16(ones4, pa[kb], lacc);
    // O += P * V : V b64 reads.
#pragma unroll
    for (int kb = 0; kb < 4; ++kb)
#pragma unroll
      for (int jd = 0; jd < 4; ++jd) {
        const short4v bv = *(const short4v*)(Vb + jd * 1024 + vbase[kb]);
        o[jd] = MFMA16K16(pa[kb], bv, o[jd]);
      }
    buf += 1; if (buf >= 3) buf -= 3;
  }

  // lacc: D[m][q] all-rows-equal = lsum[q = lane&15]; redistribute to rows
  const int b = bh >> 4, h = bh & 15;
  float inv[4];
#pragma unroll
  for (int r = 0; r < 4; ++r)
    inv[r] = __builtin_amdgcn_rcpf(__shfl(lacc[0], quad * 4 + r));
#pragma unroll
  for (int jd = 0; jd < 4; ++jd)
#pragma unroll
    for (int r = 0; r < 4; ++r) {
      const int t = qrow0 + wave * 16 + quad * 4 + r;
      yb[((size_t)b * 2048 + t) * 1024 + h * 64 + jd * 16 + lr] =
          f2bf(o[jd][r] * inv[r]);
    }
}

extern "C" void kernel_launch(void* const* d_in, const int* in_sizes, int n_in,
                              void* d_out, int out_size, void* d_ws, size_t ws_size,
                              hipStream_t stream) {
  const float* x     = (const float*)d_in[0];   // (2,2048,1024)
  const float* Wqkv  = (const float*)d_in[1];   // (1024,3072)
  const float* bqkv  = (const float*)d_in[2];   // (3072,)
  const float* Wproj = (const float*)d_in[3];   // (1024,1024)
  const float* bproj = (const float*)d_in[4];   // (1024,)
  float* out = (float*)d_out;                   // (2,2048,1024) fp32

  char* ws = (char*)d_ws;
  unsigned short* xb     = (unsigned short*)(ws);              //  8.0 MB: x bf16 (4096x1024)
  unsigned short* wqkvT  = (unsigned short*)(ws + 8388608);    //  6.0 MB: Wqkv^T bf16 (3072x1024)
  unsigned short* wprojT = (unsigned short*)(ws + 14680064);   //  2.0 MB: Wproj^T bf16 (1024x1024)
  unsigned short* qbuf   = (unsigned short*)(ws + 16777216);   //  8.0 MB: Q (B,H,T,D), pre-scaled
  unsigned short* kbuf   = (unsigned short*)(ws + 25165824);   //  8.0 MB: K (B,H,T,D)
  unsigned short* vTbuf  = (unsigned short*)(ws + 33554432);   //  8.0 MB: V^T (B,H,D,T)
  unsigned short* ybuf   = (unsigned short*)(ws + 41943040);   //  8.0 MB: y (B,T,C) bf16

  conv_bf16<<<4096, 256, 0, stream>>>(x, xb, 4194304);
  transpose_conv<<<dim3(48, 16), 256, 0, stream>>>(Wqkv, wqkvT, 1024, 3072);
  transpose_conv<<<dim3(16, 16), 256, 0, stream>>>(Wproj, wprojT, 1024, 1024);
  gemm_bt<0, 64><<<dim3(24, 64), 256, 0, stream>>>(xb, wqkvT, bqkv, nullptr,
                                                   qbuf, kbuf, vTbuf, 3072, 1024);
  attn<<<dim3(32, 32), 256, 0, stream>>>(qbuf, kbuf, vTbuf, ybuf);
  gemm_bt<1, 64><<<dim3(8, 64), 256, 0, stream>>>(ybuf, wprojT, bproj, out,
                                                  nullptr, nullptr, nullptr, 1024, 1024);
}

// Round 3
// 186.753 us; speedup vs baseline: 1.0089x; 1.0089x over previous
//
#include <hip/hip_runtime.h>

// CausalSelfAttention on MI355X (gfx950), bf16 MFMA pipeline.
// B=2 T=2048 C=1024 NH=16 HD=64.  M=B*T=4096.

typedef __attribute__((ext_vector_type(8))) short short8;   // 8 x bf16 (4 VGPR)
typedef __attribute__((ext_vector_type(4))) short short4v;  // 4 x bf16 (2 VGPR)
typedef __attribute__((ext_vector_type(4))) float f32x4;    // MFMA 16x16 acc
typedef __attribute__((ext_vector_type(2))) unsigned int u32x2;
struct ushort4_t { unsigned short x, y, z, w; };

#define MFMA16(a, b, c) __builtin_amdgcn_mfma_f32_16x16x32_bf16((a), (b), (c), 0, 0, 0)
#define MFMA16K16(a, b, c) __builtin_amdgcn_mfma_f32_16x16x16bf16_1k((a), (b), (c), 0, 0, 0)

__device__ __forceinline__ unsigned short f2bf(float f) {
  unsigned u = __builtin_bit_cast(unsigned, f);
  u += 0x7fffu + ((u >> 16) & 1u);   // RNE
  return (unsigned short)(u >> 16);
}

__device__ __forceinline__ unsigned short f2bf_fast(float f) {
  // round-half-up: cheaper (2 VALU); |err| <= 2^-9 rel, fine for P/y
  return (unsigned short)((__builtin_bit_cast(unsigned, f) + 0x8000u) >> 16);
}

#if __has_builtin(__builtin_amdgcn_cvt_pk_bf16_f32)
typedef __attribute__((ext_vector_type(2))) __bf16 bf16x2;
__device__ __forceinline__ short4v pack_bf16x4(float a, float b, float c, float d) {
  bf16x2 lo = __builtin_amdgcn_cvt_pk_bf16_f32(a, b);
  bf16x2 hi = __builtin_amdgcn_cvt_pk_bf16_f32(c, d);
  u32x2 t;
  t[0] = __builtin_bit_cast(unsigned, lo);
  t[1] = __builtin_bit_cast(unsigned, hi);
  return __builtin_bit_cast(short4v, t);
}
#else
__device__ __forceinline__ short4v pack_bf16x4(float a, float b, float c, float d) {
  short4v r;
  r[0] = (short)f2bf_fast(a); r[1] = (short)f2bf_fast(b);
  r[2] = (short)f2bf_fast(c); r[3] = (short)f2bf_fast(d);
  return r;
}
#endif

__device__ __forceinline__ void gl2lds16(const void* g, void* l) {
  // async global->LDS, 16B/lane; LDS dest = wave-uniform base + lane*16
  __builtin_amdgcn_global_load_lds(
      (__attribute__((address_space(1))) void*)g,
      (__attribute__((address_space(3))) void*)l,
      16, 0, 0);
}

// ---------------- fp32 -> bf16 flat convert ----------------
__global__ __launch_bounds__(256) void conv_bf16(const float* __restrict__ src,
                                                 unsigned short* __restrict__ dst,
                                                 int n) {
  int i = (blockIdx.x * 256 + threadIdx.x) * 4;
  if (i >= n) return;
  float4 f = *(const float4*)(src + i);
  unsigned long long r = (unsigned long long)f2bf(f.x)
      | ((unsigned long long)f2bf(f.y) << 16)
      | ((unsigned long long)f2bf(f.z) << 32)
      | ((unsigned long long)f2bf(f.w) << 48);
  *(unsigned long long*)(dst + i) = r;
}

// ---------------- fp32 (K x N) -> bf16 transposed (N x K) ----------------
__global__ __launch_bounds__(256) void transpose_conv(const float* __restrict__ W,
                                                      unsigned short* __restrict__ WT,
                                                      int K, int N) {
  __shared__ float tile[64][65];
  const int n0 = blockIdx.x * 64, k0 = blockIdx.y * 64;
  const int tid = threadIdx.x;
  const int c = tid & 63, rbase = tid >> 6;  // 4 rows per pass, 16 passes
#pragma unroll
  for (int i = 0; i < 16; ++i) {
    int r = i * 4 + rbase;
    tile[r][c] = W[(size_t)(k0 + r) * N + n0 + c];
  }
  __syncthreads();
#pragma unroll
  for (int i = 0; i < 16; ++i) {
    int r = i * 4 + rbase;
    WT[(size_t)(n0 + r) * K + k0 + c] = f2bf(tile[c][r]);
  }
}

// ---------------- GEMM: C = A(MxK) * BT(NxK)^T ----------------
// BK=64, XOR-swizzled LDS staging (conflict-free ds_read_b128 fragments).
// MT = M-tile (128 or 64); N-tile fixed 128.
// R14 (this round): post-mortem of R13's regression — MT=64 halved per-block
// arithmetic intensity (16 MFMA/K-step) and doubled B-panel re-fetch
// (FETCH 35.9->40.4 MB); triple-buffer LDS (72 KB) cut occupancy to 18.7%.
// Keep the counted-vmcnt single-barrier pipeline but restore MT=128 and use
// DOUBLE buffering (64 KB -> 2 blocks/CU): the T3 "minimum 2-phase" recipe.
// Per K-tile: { issue stage(kt+1) -> ds_read+MFMA tile kt -> vmcnt(0) ->
// s_barrier }.  Stage latency (~200-400 cyc L2) hides UNDER the 32-MFMA
// compute phase; one barrier per tile (old structure: drain BEFORE compute
// + 2 barriers).  Buffer-overwrite safety: stage of iter kt+1 overwrites the
// buffer computed in iter kt; the end-of-iter-kt barrier proves all waves'
// reads completed (reads feed MFMAs that precede the barrier) — same
// argument as the attn pipeline, race-screened since R11.
// EPI==0: QKV epilogue -> q (B,H,T,D) PRE-SCALED by 0.125*log2(e),
//         k (B,H,T,D), v (B,H,D,T) bf16 (v packed as ushort4)
// EPI==1: proj epilogue -> fp32 out + bias
template <int EPI, int MT>
__global__ __launch_bounds__(256)
void gemm_bt(const unsigned short* __restrict__ A,
             const unsigned short* __restrict__ BT,
             const float* __restrict__ bias,
             float* __restrict__ outF,
             unsigned short* __restrict__ q_out,
             unsigned short* __restrict__ k_out,
             unsigned short* __restrict__ vT_out,
             int Ndim, int Kdim) {
  constexpr int IF = MT / 32;                 // A-frags per wave per ksub
  constexpr int RA = MT / 32;                 // A staging rounds (32 rows each)
  __shared__ __align__(16) unsigned short As[2][MT * 64];
  __shared__ __align__(16) unsigned short Bs[2][128 * 64];
  const int tid = threadIdx.x;
  const int wave = tid >> 6, lane = tid & 63;
  const int quad = lane >> 4, lr = lane & 15;
  const int wm = wave >> 1, wn = wave & 1;
  const int m0 = blockIdx.y * MT, n0 = blockIdx.x * 128;

  const int r_l = tid >> 3;
  const int cg = (tid & 7) ^ (r_l & 7);
  const unsigned short* gA = A + (size_t)(m0 + r_l) * Kdim + cg * 8;
  const unsigned short* gB = BT + (size_t)(n0 + r_l) * Kdim + cg * 8;
  const size_t rstep = (size_t)32 * Kdim;
  const int NT = Kdim >> 6;                   // K-tiles of 64

  auto stageT = [&](int bufi, int kt) {
#pragma unroll
    for (int rd = 0; rd < RA; ++rd)
      gl2lds16(gA + kt * 64 + rd * rstep, &As[bufi][rd * 2048 + wave * 512]);
#pragma unroll
    for (int rd = 0; rd < 4; ++rd)
      gl2lds16(gB + kt * 64 + rd * rstep, &Bs[bufi][rd * 2048 + wave * 512]);
  };

  f32x4 acc[IF][4] = {};
  stageT(0, 0);
  __builtin_amdgcn_s_waitcnt(0x0F70);         // vmcnt(0): tile 0 in LDS
  __builtin_amdgcn_s_barrier();
  int cur = 0;
  for (int kt = 0; kt < NT; ++kt) {
    if (kt + 1 < NT) stageT(cur ^ 1, kt + 1); // issue next-tile DMA FIRST
    const unsigned short* Ab = As[cur];
    const unsigned short* Bb = Bs[cur];
#pragma unroll
    for (int s = 0; s < 2; ++s) {
      const int sw = ((s * 4 + quad) ^ (lr & 7)) * 8;
      short8 a[IF], b[4];
#pragma unroll
      for (int i = 0; i < IF; ++i)
        a[i] = *(const short8*)(Ab + (wm * (MT / 2) + i * 16 + lr) * 64 + sw);
#pragma unroll
      for (int j = 0; j < 4; ++j)
        b[j] = *(const short8*)(Bb + (wn * 64 + j * 16 + lr) * 64 + sw);
#pragma unroll
      for (int i = 0; i < IF; ++i)
#pragma unroll
        for (int j = 0; j < 4; ++j)
          acc[i][j] = MFMA16(a[i], b[j], acc[i][j]);
    }
    if (kt + 1 < NT) {
      __builtin_amdgcn_s_waitcnt(0x0F70);     // vmcnt(0): stage kt+1 landed
      __builtin_amdgcn_s_barrier();           // all waves done reading As[cur]
    }
    cur ^= 1;
  }

  // C/D layout: col = lane&15, row = quad*4 + reg
  const int row_t = wm * (MT / 2) + quad * 4;
  const int col_t = wn * 64 + lr;
  if (EPI == 0) {
    const int sec = n0 >> 10;                 // block-uniform
    const float scl = (sec == 0) ? 0.18033688f : 1.0f;  // fold 0.125*log2(e) into Q
#pragma unroll
    for (int j = 0; j < 4; ++j) {
      const int n = n0 + col_t + j * 16;
      const float bi = bias[n];
      const int nn = n & 1023, h = nn >> 6, d = nn & 63;
#pragma unroll
      for (int i = 0; i < IF; ++i) {
        const int m_base = m0 + row_t + i * 16;   // 4 consecutive m for r=0..3
        const int bb = m_base >> 11, t0 = m_base & 2047;
        const int bh = bb * 16 + h;
        if (sec == 2) {
          ushort4_t pk;
          pk.x = f2bf(acc[i][j][0] + bi);
          pk.y = f2bf(acc[i][j][1] + bi);
          pk.z = f2bf(acc[i][j][2] + bi);
          pk.w = f2bf(acc[i][j][3] + bi);
          *(ushort4_t*)(vT_out + ((size_t)bh * 64 + d) * 2048 + t0) = pk;
        } else {
          unsigned short* dst = (sec == 0 ? q_out : k_out) + (size_t)bh * 131072 + t0 * 64 + d;
#pragma unroll
          for (int r = 0; r < 4; ++r)
            dst[r * 64] = f2bf((acc[i][j][r] + bi) * scl);
        }
      }
    }
  } else {
#pragma unroll
    for (int i = 0; i < IF; ++i)
#pragma unroll
      for (int r = 0; r < 4; ++r) {
        const int m = m0 + row_t + i * 16 + r;
#pragma unroll
        for (int j = 0; j < 4; ++j) {
          const int n = n0 + col_t + j * 16;
          outF[(size_t)m * Ndim + n] = acc[i][j][r] + bias[n];
        }
      }
  }
}

// ---------------- flash-style causal attention, 64-row q-tiles ----------------
// m=0 softmax; Q PRE-SCALED by 0.125*log2(e) so P = exp2(S).
// Transposed-S trick: S^T = K*Q^T; its C-layout IS the K=16 A-operand layout.
// Block = 4 waves x 16 q-rows = 64 q-rows; K/V fragment LDS reads shared.
// 1024 blocks, heavy-first (LPT) dispatch, bh%8 pins XCD for K/V L2 locality.
// Triple-buffered K/V staged TWO tiles ahead; raw s_barrier + manual
// s_waitcnt vmcnt(4) so the newest stage stays in flight across the barrier.
// q,k: (B,H,T,D); v: (B,H,D,T); y: (B,T,C).
__global__ __launch_bounds__(256, 3)
void attn(const unsigned short* __restrict__ qbuf,
          const unsigned short* __restrict__ kbuf,
          const unsigned short* __restrict__ vT,
          unsigned short* __restrict__ yb) {
  __shared__ __align__(16) unsigned short Ks[3][4096];
  __shared__ __align__(16) unsigned short Vs[3][4096];
  const int tid = threadIdx.x, wave = tid >> 6, lane = tid & 63;
  const int quad = lane >> 4, lr = lane & 15;
  const int bh = blockIdx.x;                  // heads fastest: bh%8 pins XCD
  const int qt = 31 - (int)blockIdx.y;        // heavy-first for refill (LPT)
  const int qrow0 = qt * 64;                  // tile base (head-local)

  const unsigned short* qp0 = qbuf + (size_t)bh * 131072;
  const unsigned short* kp0 = kbuf + (size_t)bh * 131072;
  const unsigned short* vp0 = vT   + (size_t)bh * 131072;

  // Q fragments (B-operand of S^T: n = q = lane&15, k = d = quad*8+j)
  short8 aq[2];
  {
    const unsigned short* qp =
        qp0 + (size_t)(qrow0 + wave * 16 + lr) * 64 + quad * 8;
    aq[0] = *(const short8*)qp;
    aq[1] = *(const short8*)(qp + 32);
  }

  short4v ones4;
#pragma unroll
  for (int i = 0; i < 4; ++i) ones4[i] = (short)0x3F80;  // bf16 1.0

  // DMA staging: thread t -> (row=t>>3 in 0..31 (+32), cg=(t&7)^(row&7))
  const int sr = tid >> 3;
  const int scg = (tid & 7) ^ (sr & 7);
  // K fragment bases (A-operand: m = key = lr (+jt*16), k = d = (quad+4h)*8), swizzled
  int kbase[2];
#pragma unroll
  for (int h = 0; h < 2; ++h)
    kbase[h] = lr * 64 + (((quad + 4 * h) ^ (lr & 7)) << 3);
  // V b64 bases per key-block kb: element (row = d = lr (+jd*16), col = kb*16+quad*4)
  int vbase[4];
#pragma unroll
  for (int kb = 0; kb < 4; ++kb)
    vbase[kb] = lr * 64 + (((2 * kb + (quad >> 1)) ^ (lr & 7)) << 3) + (quad & 1) * 4;

  f32x4 o[4] = {};
  f32x4 lacc = {};

  auto stage = [&](int buf, int kt) {
    const unsigned short* kg = kp0 + (size_t)(kt * 64 + sr) * 64 + scg * 8;
    const unsigned short* vg = vp0 + (size_t)sr * 2048 + kt * 64 + scg * 8;
    gl2lds16(kg,             &Ks[buf][wave * 512]);
    gl2lds16(kg + 32 * 64,   &Ks[buf][2048 + wave * 512]);
    gl2lds16(vg,             &Vs[buf][wave * 512]);
    gl2lds16(vg + 32 * 2048, &Vs[buf][2048 + wave * 512]);
  };

  const int dlast = qt;           // diagonal k-tile index == last tile
  stage(0, 0);
  if (dlast >= 1) stage(1, 1);
  int buf = 0;
  for (int kt = 0; kt <= dlast; ++kt) {
    // Drain own DMAs for tile kt (issued 2 iters ago) but keep the newest
    // stage (4 instrs, tile kt+1) in flight. Each wave drains its own; the
    // barrier then guarantees all waves' contributions to tile kt are in LDS.
    if (kt < dlast) __builtin_amdgcn_s_waitcnt(0x0F74);  // vmcnt(4)
    else            __builtin_amdgcn_s_waitcnt(0x0F70);  // vmcnt(0)
    __builtin_amdgcn_s_barrier();
    if (kt + 2 <= dlast) {
      int nb = buf + 2; if (nb >= 3) nb -= 3;
      stage(nb, kt + 2);          // overwrites buffer of tile kt-1 (consumed)
    }
    const unsigned short* Kb = Ks[buf];
    const unsigned short* Vb = Vs[buf];
    short8 bk[4][2];
#pragma unroll
    for (int jt = 0; jt < 4; ++jt) {
      bk[jt][0] = *(const short8*)(Kb + jt * 1024 + kbase[0]);
      bk[jt][1] = *(const short8*)(Kb + jt * 1024 + kbase[1]);
    }
    // S^T, exp2 (+causal mask on the diagonal tile), pack; lsum.
    f32x4 s[4] = {};
#pragma unroll
    for (int jt = 0; jt < 4; ++jt) {
      s[jt] = MFMA16(bk[jt][0], aq[0], s[jt]);
      s[jt] = MFMA16(bk[jt][1], aq[1], s[jt]);
    }
    short4v pa[4];
    if (kt == dlast) {            // diagonal: key-local > wave*16+lr masked
      const int qloc = wave * 16 + lr;
#pragma unroll
      for (int jt = 0; jt < 4; ++jt) {
        float p[4];
#pragma unroll
        for (int r = 0; r < 4; ++r) {
          p[r] = __builtin_amdgcn_exp2f(s[jt][r]);
          if (jt * 16 + quad * 4 + r > qloc) p[r] = 0.f;
        }
        pa[jt] = pack_bf16x4(p[0], p[1], p[2], p[3]);
      }
    } else {
#pragma unroll
      for (int jt = 0; jt < 4; ++jt) {
        float p[4];
#pragma unroll
        for (int r = 0; r < 4; ++r) p[r] = __builtin_amdgcn_exp2f(s[jt][r]);
        pa[jt] = pack_bf16x4(p[0], p[1], p[2], p[3]);
      }
    }
#pragma unroll
    for (int kb = 0; kb < 4; ++kb)
      lacc = MFMA16K16(ones4, pa[kb], lacc);
    // O += P * V : V b64 reads.
#pragma unroll
    for (int kb = 0; kb < 4; ++kb)
#pragma unroll
      for (int jd = 0; jd < 4; ++jd) {
        const short4v bv = *(const short4v*)(Vb + jd * 1024 + vbase[kb]);
        o[jd] = MFMA16K16(pa[kb], bv, o[jd]);
      }
    buf += 1; if (buf >= 3) buf -= 3;
  }

  // lacc: D[m][q] all-rows-equal = lsum[q = lane&15]; redistribute to rows
  const int b = bh >> 4, h = bh & 15;
  float inv[4];
#pragma unroll
  for (int r = 0; r < 4; ++r)
    inv[r] = __builtin_amdgcn_rcpf(__shfl(lacc[0], quad * 4 + r));
#pragma unroll
  for (int jd = 0; jd < 4; ++jd)
#pragma unroll
    for (int r = 0; r < 4; ++r) {
      const int t = qrow0 + wave * 16 + quad * 4 + r;
      yb[((size_t)b * 2048 + t) * 1024 + h * 64 + jd * 16 + lr] =
          f2bf(o[jd][r] * inv[r]);
    }
}

extern "C" void kernel_launch(void* const* d_in, const int* in_sizes, int n_in,
                              void* d_out, int out_size, void* d_ws, size_t ws_size,
                              hipStream_t stream) {
  const float* x     = (const float*)d_in[0];   // (2,2048,1024)
  const float* Wqkv  = (const float*)d_in[1];   // (1024,3072)
  const float* bqkv  = (const float*)d_in[2];   // (3072,)
  const float* Wproj = (const float*)d_in[3];   // (1024,1024)
  const float* bproj = (const float*)d_in[4];   // (1024,)
  float* out = (float*)d_out;                   // (2,2048,1024) fp32

  char* ws = (char*)d_ws;
  unsigned short* xb     = (unsigned short*)(ws);              //  8.0 MB: x bf16 (4096x1024)
  unsigned short* wqkvT  = (unsigned short*)(ws + 8388608);    //  6.0 MB: Wqkv^T bf16 (3072x1024)
  unsigned short* wprojT = (unsigned short*)(ws + 14680064);   //  2.0 MB: Wproj^T bf16 (1024x1024)
  unsigned short* qbuf   = (unsigned short*)(ws + 16777216);   //  8.0 MB: Q (B,H,T,D), pre-scaled
  unsigned short* kbuf   = (unsigned short*)(ws + 25165824);   //  8.0 MB: K (B,H,T,D)
  unsigned short* vTbuf  = (unsigned short*)(ws + 33554432);   //  8.0 MB: V^T (B,H,D,T)
  unsigned short* ybuf   = (unsigned short*)(ws + 41943040);   //  8.0 MB: y (B,T,C) bf16

  conv_bf16<<<4096, 256, 0, stream>>>(x, xb, 4194304);
  transpose_conv<<<dim3(48, 16), 256, 0, stream>>>(Wqkv, wqkvT, 1024, 3072);
  transpose_conv<<<dim3(16, 16), 256, 0, stream>>>(Wproj, wprojT, 1024, 1024);
  gemm_bt<0, 128><<<dim3(24, 32), 256, 0, stream>>>(xb, wqkvT, bqkv, nullptr,
                                                    qbuf, kbuf, vTbuf, 3072, 1024);
  attn<<<dim3(32, 32), 256, 0, stream>>>(qbuf, kbuf, vTbuf, ybuf);
  gemm_bt<1, 64><<<dim3(8, 64), 256, 0, stream>>>(ybuf, wprojT, bproj, out,
                                                  nullptr, nullptr, nullptr, 1024, 1024);
}

// Round 4
// 177.319 us; speedup vs baseline: 1.0626x; 1.0532x over previous
//
#include <hip/hip_runtime.h>

// CausalSelfAttention on MI355X (gfx950), bf16 MFMA pipeline.
// B=2 T=2048 C=1024 NH=16 HD=64.  M=B*T=4096.
//
// R15: post-mortem of R13/R14 — both pipelined-GEMM variants regressed
// because LDS growth (64-72 KB) cut block residency from ~3/CU to 2/CU;
// cross-block TLP (m114: separate waves' MFMA/VALU/VMEM co-schedule) was
// the real latency-hiding mechanism, and it beats within-block pipelining
// at this shape.  Reverted to the R1 GEMM exactly (32 KB LDS, 2 barriers
// per K-step, 537 TF).  New this round: (a) the three prep kernels merged
// into ONE dispatch (removes 2 kernel-boundary gaps); (b) T5 s_setprio(1)
// around attn's MFMA clusters (attn blocks are independent => the regime
// where setprio measured +4-7%; null on lockstep GEMMs so not applied there).

typedef __attribute__((ext_vector_type(8))) short short8;   // 8 x bf16 (4 VGPR)
typedef __attribute__((ext_vector_type(4))) short short4v;  // 4 x bf16 (2 VGPR)
typedef __attribute__((ext_vector_type(4))) float f32x4;    // MFMA 16x16 acc
typedef __attribute__((ext_vector_type(2))) unsigned int u32x2;
struct ushort4_t { unsigned short x, y, z, w; };

#define MFMA16(a, b, c) __builtin_amdgcn_mfma_f32_16x16x32_bf16((a), (b), (c), 0, 0, 0)
#define MFMA16K16(a, b, c) __builtin_amdgcn_mfma_f32_16x16x16bf16_1k((a), (b), (c), 0, 0, 0)

__device__ __forceinline__ unsigned short f2bf(float f) {
  unsigned u = __builtin_bit_cast(unsigned, f);
  u += 0x7fffu + ((u >> 16) & 1u);   // RNE
  return (unsigned short)(u >> 16);
}

__device__ __forceinline__ unsigned short f2bf_fast(float f) {
  // round-half-up: cheaper (2 VALU); |err| <= 2^-9 rel, fine for P/y
  return (unsigned short)((__builtin_bit_cast(unsigned, f) + 0x8000u) >> 16);
}

#if __has_builtin(__builtin_amdgcn_cvt_pk_bf16_f32)
typedef __attribute__((ext_vector_type(2))) __bf16 bf16x2;
__device__ __forceinline__ short4v pack_bf16x4(float a, float b, float c, float d) {
  bf16x2 lo = __builtin_amdgcn_cvt_pk_bf16_f32(a, b);
  bf16x2 hi = __builtin_amdgcn_cvt_pk_bf16_f32(c, d);
  u32x2 t;
  t[0] = __builtin_bit_cast(unsigned, lo);
  t[1] = __builtin_bit_cast(unsigned, hi);
  return __builtin_bit_cast(short4v, t);
}
#else
__device__ __forceinline__ short4v pack_bf16x4(float a, float b, float c, float d) {
  short4v r;
  r[0] = (short)f2bf_fast(a); r[1] = (short)f2bf_fast(b);
  r[2] = (short)f2bf_fast(c); r[3] = (short)f2bf_fast(d);
  return r;
}
#endif

__device__ __forceinline__ void gl2lds16(const void* g, void* l) {
  // async global->LDS, 16B/lane; LDS dest = wave-uniform base + lane*16
  __builtin_amdgcn_global_load_lds(
      (__attribute__((address_space(1))) void*)g,
      (__attribute__((address_space(3))) void*)l,
      16, 0, 0);
}

// ---------------- merged prep: x->bf16 + both weight transposes ----------------
// blocks [0,4096): conv x (4096x1024 fp32 -> bf16)
// blocks [4096,4864): Wqkv (1024x3072) -> Wqkv^T bf16 (3072x1024), 48x16 tiles
// blocks [4864,5120): Wproj (1024x1024) -> Wproj^T bf16, 16x16 tiles
// Branch is block-uniform, so the __syncthreads in the transpose path is safe.
__global__ __launch_bounds__(256)
void prep(const float* __restrict__ x, unsigned short* __restrict__ xb,
          const float* __restrict__ Wqkv, unsigned short* __restrict__ wqkvT,
          const float* __restrict__ Wproj, unsigned short* __restrict__ wprojT) {
  __shared__ float tile[64][65];
  const int bx = blockIdx.x, tid = threadIdx.x;
  if (bx < 4096) {
    const int i = (bx * 256 + tid) * 4;
    float4 f = *(const float4*)(x + i);
    unsigned long long r = (unsigned long long)f2bf(f.x)
        | ((unsigned long long)f2bf(f.y) << 16)
        | ((unsigned long long)f2bf(f.z) << 32)
        | ((unsigned long long)f2bf(f.w) << 48);
    *(unsigned long long*)(xb + i) = r;
    return;
  }
  const float* W;
  unsigned short* WT;
  int n0, k0, N;
  if (bx < 4864) {
    const int idx = bx - 4096;            // 48 x 16 tiles, N=3072
    W = Wqkv; WT = wqkvT; N = 3072;
    n0 = (idx % 48) * 64; k0 = (idx / 48) * 64;
  } else {
    const int idx = bx - 4864;            // 16 x 16 tiles, N=1024
    W = Wproj; WT = wprojT; N = 1024;
    n0 = (idx % 16) * 64; k0 = (idx / 16) * 64;
  }
  const int K = 1024;
  const int c = tid & 63, rbase = tid >> 6;  // 4 rows per pass, 16 passes
#pragma unroll
  for (int i = 0; i < 16; ++i) {
    int r = i * 4 + rbase;
    tile[r][c] = W[(size_t)(k0 + r) * N + n0 + c];
  }
  __syncthreads();
#pragma unroll
  for (int i = 0; i < 16; ++i) {
    int r = i * 4 + rbase;
    WT[(size_t)(n0 + r) * K + k0 + c] = f2bf(tile[c][r]);
  }
}

// ---------------- GEMM: C = A(MxK) * BT(NxK)^T ----------------
// BK=64, XOR-swizzled LDS staging (conflict-free ds_read_b128 fragments).
// MT = M-tile (128 or 64); N-tile fixed 128.  R1 structure (proven best):
// single-buffered 32 KB LDS -> ~3 blocks/CU; stage -> sync -> compute -> sync.
// Cross-block TLP hides the stage drain (R13/R14 showed pipelining that costs
// LDS loses more from residency than it gains).
// EPI==0: QKV epilogue -> q (B,H,T,D) PRE-SCALED by 0.125*log2(e),
//         k (B,H,T,D), v (B,H,D,T) bf16 (v packed as ushort4)
// EPI==1: proj epilogue -> fp32 out + bias
template <int EPI, int MT>
__global__ __launch_bounds__(256)
void gemm_bt(const unsigned short* __restrict__ A,
             const unsigned short* __restrict__ BT,
             const float* __restrict__ bias,
             float* __restrict__ outF,
             unsigned short* __restrict__ q_out,
             unsigned short* __restrict__ k_out,
             unsigned short* __restrict__ vT_out,
             int Ndim, int Kdim) {
  constexpr int IF = MT / 32;                 // A-frags per wave per ksub
  constexpr int RA = MT / 32;                 // A staging rounds (32 rows each)
  __shared__ __align__(16) unsigned short As[MT * 64];
  __shared__ __align__(16) unsigned short Bs[128 * 64];
  const int tid = threadIdx.x;
  const int wave = tid >> 6, lane = tid & 63;
  const int quad = lane >> 4, lr = lane & 15;
  const int wm = wave >> 1, wn = wave & 1;
  const int m0 = blockIdx.y * MT, n0 = blockIdx.x * 128;

  const int r_l = tid >> 3;
  const int cg = (tid & 7) ^ (r_l & 7);
  const unsigned short* gA = A + (size_t)(m0 + r_l) * Kdim + cg * 8;
  const unsigned short* gB = BT + (size_t)(n0 + r_l) * Kdim + cg * 8;
  const size_t rstep = (size_t)32 * Kdim;

  f32x4 acc[IF][4] = {};
  for (int k0 = 0; k0 < Kdim; k0 += 64) {
#pragma unroll
    for (int rd = 0; rd < RA; ++rd)
      gl2lds16(gA + k0 + rd * rstep, As + rd * 2048 + wave * 512);
#pragma unroll
    for (int rd = 0; rd < 4; ++rd)
      gl2lds16(gB + k0 + rd * rstep, Bs + rd * 2048 + wave * 512);
    __syncthreads();
#pragma unroll
    for (int s = 0; s < 2; ++s) {
      const int sw = ((s * 4 + quad) ^ (lr & 7)) * 8;
      short8 a[IF], b[4];
#pragma unroll
      for (int i = 0; i < IF; ++i)
        a[i] = *(const short8*)(As + (wm * (MT / 2) + i * 16 + lr) * 64 + sw);
#pragma unroll
      for (int j = 0; j < 4; ++j)
        b[j] = *(const short8*)(Bs + (wn * 64 + j * 16 + lr) * 64 + sw);
#pragma unroll
      for (int i = 0; i < IF; ++i)
#pragma unroll
        for (int j = 0; j < 4; ++j)
          acc[i][j] = MFMA16(a[i], b[j], acc[i][j]);
    }
    __syncthreads();
  }

  // C/D layout: col = lane&15, row = quad*4 + reg
  const int row_t = wm * (MT / 2) + quad * 4;
  const int col_t = wn * 64 + lr;
  if (EPI == 0) {
    const int sec = n0 >> 10;                 // block-uniform
    const float scl = (sec == 0) ? 0.18033688f : 1.0f;  // fold 0.125*log2(e) into Q
#pragma unroll
    for (int j = 0; j < 4; ++j) {
      const int n = n0 + col_t + j * 16;
      const float bi = bias[n];
      const int nn = n & 1023, h = nn >> 6, d = nn & 63;
#pragma unroll
      for (int i = 0; i < IF; ++i) {
        const int m_base = m0 + row_t + i * 16;   // 4 consecutive m for r=0..3
        const int bb = m_base >> 11, t0 = m_base & 2047;
        const int bh = bb * 16 + h;
        if (sec == 2) {
          ushort4_t pk;
          pk.x = f2bf(acc[i][j][0] + bi);
          pk.y = f2bf(acc[i][j][1] + bi);
          pk.z = f2bf(acc[i][j][2] + bi);
          pk.w = f2bf(acc[i][j][3] + bi);
          *(ushort4_t*)(vT_out + ((size_t)bh * 64 + d) * 2048 + t0) = pk;
        } else {
          unsigned short* dst = (sec == 0 ? q_out : k_out) + (size_t)bh * 131072 + t0 * 64 + d;
#pragma unroll
          for (int r = 0; r < 4; ++r)
            dst[r * 64] = f2bf((acc[i][j][r] + bi) * scl);
        }
      }
    }
  } else {
#pragma unroll
    for (int i = 0; i < IF; ++i)
#pragma unroll
      for (int r = 0; r < 4; ++r) {
        const int m = m0 + row_t + i * 16 + r;
#pragma unroll
        for (int j = 0; j < 4; ++j) {
          const int n = n0 + col_t + j * 16;
          outF[(size_t)m * Ndim + n] = acc[i][j][r] + bias[n];
        }
      }
  }
}

// ---------------- flash-style causal attention, 64-row q-tiles ----------------
// m=0 softmax; Q PRE-SCALED by 0.125*log2(e) so P = exp2(S).
// Transposed-S trick: S^T = K*Q^T; its C-layout IS the K=16 A-operand layout.
// Block = 4 waves x 16 q-rows = 64 q-rows; K/V fragment LDS reads shared.
// 1024 blocks, heavy-first (LPT) dispatch, bh%8 pins XCD for K/V L2 locality.
// Triple-buffered K/V staged TWO tiles ahead; raw s_barrier + manual
// s_waitcnt vmcnt(4) so the newest stage stays in flight across the barrier.
// R15: s_setprio(1) wrapped around the MFMA clusters (T5) — attn blocks are
// independent (no cross-block lockstep), the regime where setprio measured
// +4-7%.
// q,k: (B,H,T,D); v: (B,H,D,T); y: (B,T,C).
__global__ __launch_bounds__(256, 3)
void attn(const unsigned short* __restrict__ qbuf,
          const unsigned short* __restrict__ kbuf,
          const unsigned short* __restrict__ vT,
          unsigned short* __restrict__ yb) {
  __shared__ __align__(16) unsigned short Ks[3][4096];
  __shared__ __align__(16) unsigned short Vs[3][4096];
  const int tid = threadIdx.x, wave = tid >> 6, lane = tid & 63;
  const int quad = lane >> 4, lr = lane & 15;
  const int bh = blockIdx.x;                  // heads fastest: bh%8 pins XCD
  const int qt = 31 - (int)blockIdx.y;        // heavy-first for refill (LPT)
  const int qrow0 = qt * 64;                  // tile base (head-local)

  const unsigned short* qp0 = qbuf + (size_t)bh * 131072;
  const unsigned short* kp0 = kbuf + (size_t)bh * 131072;
  const unsigned short* vp0 = vT   + (size_t)bh * 131072;

  // Q fragments (B-operand of S^T: n = q = lane&15, k = d = quad*8+j)
  short8 aq[2];
  {
    const unsigned short* qp =
        qp0 + (size_t)(qrow0 + wave * 16 + lr) * 64 + quad * 8;
    aq[0] = *(const short8*)qp;
    aq[1] = *(const short8*)(qp + 32);
  }

  short4v ones4;
#pragma unroll
  for (int i = 0; i < 4; ++i) ones4[i] = (short)0x3F80;  // bf16 1.0

  // DMA staging: thread t -> (row=t>>3 in 0..31 (+32), cg=(t&7)^(row&7))
  const int sr = tid >> 3;
  const int scg = (tid & 7) ^ (sr & 7);
  // K fragment bases (A-operand: m = key = lr (+jt*16), k = d = (quad+4h)*8), swizzled
  int kbase[2];
#pragma unroll
  for (int h = 0; h < 2; ++h)
    kbase[h] = lr * 64 + (((quad + 4 * h) ^ (lr & 7)) << 3);
  // V b64 bases per key-block kb: element (row = d = lr (+jd*16), col = kb*16+quad*4)
  int vbase[4];
#pragma unroll
  for (int kb = 0; kb < 4; ++kb)
    vbase[kb] = lr * 64 + (((2 * kb + (quad >> 1)) ^ (lr & 7)) << 3) + (quad & 1) * 4;

  f32x4 o[4] = {};
  f32x4 lacc = {};

  auto stage = [&](int buf, int kt) {
    const unsigned short* kg = kp0 + (size_t)(kt * 64 + sr) * 64 + scg * 8;
    const unsigned short* vg = vp0 + (size_t)sr * 2048 + kt * 64 + scg * 8;
    gl2lds16(kg,             &Ks[buf][wave * 512]);
    gl2lds16(kg + 32 * 64,   &Ks[buf][2048 + wave * 512]);
    gl2lds16(vg,             &Vs[buf][wave * 512]);
    gl2lds16(vg + 32 * 2048, &Vs[buf][2048 + wave * 512]);
  };

  const int dlast = qt;           // diagonal k-tile index == last tile
  stage(0, 0);
  if (dlast >= 1) stage(1, 1);
  int buf = 0;
  for (int kt = 0; kt <= dlast; ++kt) {
    // Drain own DMAs for tile kt (issued 2 iters ago) but keep the newest
    // stage (4 instrs, tile kt+1) in flight. Each wave drains its own; the
    // barrier then guarantees all waves' contributions to tile kt are in LDS.
    if (kt < dlast) __builtin_amdgcn_s_waitcnt(0x0F74);  // vmcnt(4)
    else            __builtin_amdgcn_s_waitcnt(0x0F70);  // vmcnt(0)
    __builtin_amdgcn_s_barrier();
    if (kt + 2 <= dlast) {
      int nb = buf + 2; if (nb >= 3) nb -= 3;
      stage(nb, kt + 2);          // overwrites buffer of tile kt-1 (consumed)
    }
    const unsigned short* Kb = Ks[buf];
    const unsigned short* Vb = Vs[buf];
    short8 bk[4][2];
#pragma unroll
    for (int jt = 0; jt < 4; ++jt) {
      bk[jt][0] = *(const short8*)(Kb + jt * 1024 + kbase[0]);
      bk[jt][1] = *(const short8*)(Kb + jt * 1024 + kbase[1]);
    }
    // S^T, exp2 (+causal mask on the diagonal tile), pack; lsum.
    f32x4 s[4] = {};
    __builtin_amdgcn_s_setprio(1);
#pragma unroll
    for (int jt = 0; jt < 4; ++jt) {
      s[jt] = MFMA16(bk[jt][0], aq[0], s[jt]);
      s[jt] = MFMA16(bk[jt][1], aq[1], s[jt]);
    }
    __builtin_amdgcn_s_setprio(0);
    short4v pa[4];
    if (kt == dlast) {            // diagonal: key-local > wave*16+lr masked
      const int qloc = wave * 16 + lr;
#pragma unroll
      for (int jt = 0; jt < 4; ++jt) {
        float p[4];
#pragma unroll
        for (int r = 0; r < 4; ++r) {
          p[r] = __builtin_amdgcn_exp2f(s[jt][r]);
          if (jt * 16 + quad * 4 + r > qloc) p[r] = 0.f;
        }
        pa[jt] = pack_bf16x4(p[0], p[1], p[2], p[3]);
      }
    } else {
#pragma unroll
      for (int jt = 0; jt < 4; ++jt) {
        float p[4];
#pragma unroll
        for (int r = 0; r < 4; ++r) p[r] = __builtin_amdgcn_exp2f(s[jt][r]);
        pa[jt] = pack_bf16x4(p[0], p[1], p[2], p[3]);
      }
    }
    __builtin_amdgcn_s_setprio(1);
#pragma unroll
    for (int kb = 0; kb < 4; ++kb)
      lacc = MFMA16K16(ones4, pa[kb], lacc);
    // O += P * V : V b64 reads.
#pragma unroll
    for (int kb = 0; kb < 4; ++kb)
#pragma unroll
      for (int jd = 0; jd < 4; ++jd) {
        const short4v bv = *(const short4v*)(Vb + jd * 1024 + vbase[kb]);
        o[jd] = MFMA16K16(pa[kb], bv, o[jd]);
      }
    __builtin_amdgcn_s_setprio(0);
    buf += 1; if (buf >= 3) buf -= 3;
  }

  // lacc: D[m][q] all-rows-equal = lsum[q = lane&15]; redistribute to rows
  const int b = bh >> 4, h = bh & 15;
  float inv[4];
#pragma unroll
  for (int r = 0; r < 4; ++r)
    inv[r] = __builtin_amdgcn_rcpf(__shfl(lacc[0], quad * 4 + r));
#pragma unroll
  for (int jd = 0; jd < 4; ++jd)
#pragma unroll
    for (int r = 0; r < 4; ++r) {
      const int t = qrow0 + wave * 16 + quad * 4 + r;
      yb[((size_t)b * 2048 + t) * 1024 + h * 64 + jd * 16 + lr] =
          f2bf(o[jd][r] * inv[r]);
    }
}

extern "C" void kernel_launch(void* const* d_in, const int* in_sizes, int n_in,
                              void* d_out, int out_size, void* d_ws, size_t ws_size,
                              hipStream_t stream) {
  const float* x     = (const float*)d_in[0];   // (2,2048,1024)
  const float* Wqkv  = (const float*)d_in[1];   // (1024,3072)
  const float* bqkv  = (const float*)d_in[2];   // (3072,)
  const float* Wproj = (const float*)d_in[3];   // (1024,1024)
  const float* bproj = (const float*)d_in[4];   // (1024,)
  float* out = (float*)d_out;                   // (2,2048,1024) fp32

  char* ws = (char*)d_ws;
  unsigned short* xb     = (unsigned short*)(ws);              //  8.0 MB: x bf16 (4096x1024)
  unsigned short* wqkvT  = (unsigned short*)(ws + 8388608);    //  6.0 MB: Wqkv^T bf16 (3072x1024)
  unsigned short* wprojT = (unsigned short*)(ws + 14680064);   //  2.0 MB: Wproj^T bf16 (1024x1024)
  unsigned short* qbuf   = (unsigned short*)(ws + 16777216);   //  8.0 MB: Q (B,H,T,D), pre-scaled
  unsigned short* kbuf   = (unsigned short*)(ws + 25165824);   //  8.0 MB: K (B,H,T,D)
  unsigned short* vTbuf  = (unsigned short*)(ws + 33554432);   //  8.0 MB: V^T (B,H,D,T)
  unsigned short* ybuf   = (unsigned short*)(ws + 41943040);   //  8.0 MB: y (B,T,C) bf16

  prep<<<5120, 256, 0, stream>>>(x, xb, Wqkv, wqkvT, Wproj, wprojT);
  gemm_bt<0, 128><<<dim3(24, 32), 256, 0, stream>>>(xb, wqkvT, bqkv, nullptr,
                                                    qbuf, kbuf, vTbuf, 3072, 1024);
  attn<<<dim3(32, 32), 256, 0, stream>>>(qbuf, kbuf, vTbuf, ybuf);
  gemm_bt<1, 64><<<dim3(8, 64), 256, 0, stream>>>(ybuf, wprojT, bproj, out,
                                                  nullptr, nullptr, nullptr, 1024, 1024);
}